// Round 8
// baseline (129.903 us; speedup 1.0000x reference)
//
#include <hip/hip_runtime.h>

typedef __bf16 bf16_t;
typedef __bf16 bf16x2 __attribute__((ext_vector_type(2)));
typedef __bf16 bf16x4 __attribute__((ext_vector_type(4)));
typedef __bf16 bf16x8 __attribute__((ext_vector_type(8)));
typedef float  f32x4  __attribute__((ext_vector_type(4)));
typedef float  f32x4u __attribute__((ext_vector_type(4), aligned(4)));
typedef unsigned int u32;

#define MFMA16(a, b, c) __builtin_amdgcn_mfma_f32_16x16x32_bf16((a), (b), (c), 0, 0, 0)

#define ROWB 272   // LDS x/att tile row stride (natural +16B stagger, 2-way = free)

// Fragment conventions for v_mfma_f32_16x16x32_bf16, D = A*B (verified r0-r7):
//  A (MxK): lane holds A[c0][8g+i], i=0..7
//  B (KxN): lane holds B[8g+i][c0]
//  D (MxN): lane reg r holds D[4g+r][c0]

union W8 { u32 u[4]; bf16x8 v; };

__device__ __forceinline__ u32 pack2(float a, float b) {
    union { bf16x2 h; u32 u; } c;
    c.h[0] = (bf16_t)a; c.h[1] = (bf16_t)b;
    return c.u;
}

__device__ __forceinline__ void st4(char* base, int row, int byteoff, bf16x4 v) {
    *(bf16x4*)(base + row * ROWB + byteoff) = v;
}
__device__ __forceinline__ bf16x8 ld8(const char* base, int row, int byteoff) {
    return *(const bf16x8*)(base + row * ROWB + byteoff);
}

// D-layout -> A/B-frag redistribution within each 4-lane c0-column (verified r3-r7).
__device__ __forceinline__ bf16x8 redist4(u32 w0, u32 w1, u32 w2, u32 w3,
                                          bool gl, bool gh) {
    u32 wd[4] = {w0, w1, w2, w3};
    u32 X[4], Y[4], Z[4];
    #pragma unroll
    for (int j = 0; j < 4; ++j) X[j] = __shfl_xor(wd[j], 16);
    #pragma unroll
    for (int j = 0; j < 4; ++j) Y[j] = __shfl_xor(wd[j], 32);
    #pragma unroll
    for (int j = 0; j < 4; ++j) Z[j] = __shfl_xor(X[j], 32);
    W8 u;
    #pragma unroll
    for (int t = 0; t < 4; ++t) {
        int j0 = t & 1;
        int j1 = j0 + 2;
        u32 lo, hi;
        if (t < 2) { lo = gl ? Z[j0] : wd[j0]; hi = gl ? X[j1] : Y[j1]; }
        else       { lo = gl ? Y[j0] : X[j0];  hi = gl ? wd[j1] : Z[j1]; }
        u.u[t] = gh ? hi : lo;
    }
    return u.v;
}

__global__ void wconv_kernel(const float* __restrict__ qw, const float* __restrict__ pw,
                             bf16_t* __restrict__ o) {
    int i = (blockIdx.x * 256 + threadIdx.x) * 4;   // 64*256*4 = 65536
    const float* src = (i < 49152) ? (qw + i) : (pw + (i - 49152));
    float4 f = *(const float4*)src;
    bf16x4 h;
    h[0] = (bf16_t)f.x; h[1] = (bf16_t)f.y; h[2] = (bf16_t)f.z; h[3] = (bf16_t)f.w;
    *(bf16x4*)(o + i) = h;
}

template<int USEB>
__device__ __forceinline__ bf16x8 ldw(const float* __restrict__ wf,
                                      const bf16_t* __restrict__ wb, int idx) {
    if constexpr (USEB) {
        return *(const bf16x8*)(wb + idx);
    } else {
        float4 f0 = *(const float4*)(wf + idx);
        float4 f1 = *(const float4*)(wf + idx + 4);
        bf16x8 r;
        r[0] = (bf16_t)f0.x; r[1] = (bf16_t)f0.y; r[2] = (bf16_t)f0.z; r[3] = (bf16_t)f0.w;
        r[4] = (bf16_t)f1.x; r[5] = (bf16_t)f1.y; r[6] = (bf16_t)f1.z; r[7] = (bf16_t)f1.w;
        return r;
    }
}

// ===================== SPLIT PATH =====================
// ws intermediate layout, bf16 elements, per window (24576 el = 48 KiB):
//   head h at +h*6144:  q[64][32] (+0)  k[64][32] (+2048)  vT[32][64] (+4096)
// q stored pre-scaled by 32^-0.5; toks 49-63 are finite garbage (handled in B).

// ---- kernel A: QKV GEMM. 256 thr; wave w owns output rows 96w..96w+95
// (two passes of 3 sixteen-row tiles; q/k tiles D[o][tok], v tiles D[tok][o]).
template<int USEB>
__global__ __launch_bounds__(256, 4) void qkv_kernel(
    const float* __restrict__ xg, const float* __restrict__ qwg,
    const float* __restrict__ qbg, const bf16_t* __restrict__ wqb,
    bf16_t* __restrict__ qkv)
{
    __shared__ char xs[17408];
    const int b    = blockIdx.x;
    const int tid  = threadIdx.x;
    const int w    = tid >> 6;
    const int lane = tid & 63;
    const int g    = lane >> 4;
    const int c0   = lane & 15;

    // stage x (49x128 f32 -> bf16 LDS); zero rows 49..63 (k/v must be finite)
    {
        const float4* xb = (const float4*)(xg + (long)b * 6272);
        #pragma unroll
        for (int it = 0; it < 7; ++it) {
            int i = tid + it * 256;
            if (i < 1568) {
                float4 f = xb[i];
                int row = i >> 5, colb = (i & 31) << 3;
                bf16x4 hq;
                hq[0] = (bf16_t)f.x; hq[1] = (bf16_t)f.y; hq[2] = (bf16_t)f.z; hq[3] = (bf16_t)f.w;
                st4(xs, row, colb, hq);
            }
        }
        #pragma unroll
        for (int it = 0; it < 4; ++it) {
            int i = tid + it * 256;
            if (i < 960) {
                int row = 49 + (i >> 6), byteo = (i & 63) << 2;
                *(u32*)(xs + row * ROWB + byteo) = 0u;
            }
        }
    }
    __syncthreads();

    bf16_t* wb = qkv + (long)b * 24576;
    const float qs = 0.17677669529663687f;   // 32^-0.5

    #pragma unroll
    for (int half = 0; half < 2; ++half) {
        f32x4 acc[3][4];
        #pragma unroll
        for (int t = 0; t < 3; ++t)
            #pragma unroll
            for (int mt = 0; mt < 4; ++mt) acc[t][mt] = {0.f, 0.f, 0.f, 0.f};

        const int jb = 3 * half;
        #pragma unroll
        for (int ks = 0; ks < 4; ++ks) {
            bf16x8 wf[3];
            #pragma unroll
            for (int t = 0; t < 3; ++t) {
                int o0 = 96 * w + 16 * (jb + t);
                wf[t] = ldw<USEB>(qwg, wqb, (o0 + c0) * 128 + 32 * ks + 8 * g);
            }
            #pragma unroll
            for (int mt = 0; mt < 4; ++mt) {
                bf16x8 xfm = ld8(xs, 16 * mt + c0, (32 * ks + 8 * g) * 2);
                #pragma unroll
                for (int t = 0; t < 3; ++t) {
                    int o0 = 96 * w + 16 * (jb + t);
                    if (o0 < 256) acc[t][mt] = MFMA16(wf[t], xfm, acc[t][mt]); // D[o][tok]
                    else          acc[t][mt] = MFMA16(xfm, wf[t], acc[t][mt]); // D[tok][o]
                }
            }
        }
        // scatter
        #pragma unroll
        for (int t = 0; t < 3; ++t) {
            int o0   = 96 * w + 16 * (jb + t);
            int part = o0 >> 7;                 // 0=q 1=k 2=v (wave-uniform)
            int hh   = (o0 >> 5) & 3;
            bf16_t* hb = wb + hh * 6144;
            if (part < 2) {
                // D[o][tok]: reg r -> o=o0+4g+r, tok=16mt+c0
                float4 b4 = *(const float4*)(qbg + o0 + 4 * g);
                float sc  = (part == 0) ? qs : 1.f;
                bf16_t* dst = hb + (part == 0 ? 0 : 2048);
                int dh0 = (o0 & 31) + 4 * g;
                #pragma unroll
                for (int mt = 0; mt < 4; ++mt) {
                    int tok = 16 * mt + c0;
                    bf16x4 tv;
                    tv[0] = (bf16_t)((acc[t][mt][0] + b4.x) * sc);
                    tv[1] = (bf16_t)((acc[t][mt][1] + b4.y) * sc);
                    tv[2] = (bf16_t)((acc[t][mt][2] + b4.z) * sc);
                    tv[3] = (bf16_t)((acc[t][mt][3] + b4.w) * sc);
                    *(bf16x4*)(dst + tok * 32 + dh0) = tv;      // q/k[tok][dh]
                }
            } else {
                // D[tok][o]: reg r -> tok=16mt+4g+r, o=o0+c0
                float bv = qbg[o0 + c0];
                bf16_t* dst = hb + 4096;
                int dh = (o0 & 31) + c0;
                #pragma unroll
                for (int mt = 0; mt < 4; ++mt) {
                    bf16x4 tv;
                    tv[0] = (bf16_t)(acc[t][mt][0] + bv);
                    tv[1] = (bf16_t)(acc[t][mt][1] + bv);
                    tv[2] = (bf16_t)(acc[t][mt][2] + bv);
                    tv[3] = (bf16_t)(acc[t][mt][3] + bv);
                    *(bf16x4*)(dst + dh * 64 + 16 * mt + 4 * g) = tv;  // vT[dh][tok]
                }
            }
        }
    }
}

// ---- kernel B: attention + proj. 256 thr; wave = head. ----
template<int USEB>
__global__ __launch_bounds__(256, 4) void attn_kernel(
    const bf16_t* __restrict__ qkv, const float* __restrict__ maskg,
    const float* __restrict__ pwg, const float* __restrict__ pbg,
    const bf16_t* __restrict__ wpb, const int nW, float* __restrict__ outg)
{
    __shared__ char as_[17408];   // att [64][136]

    const int b    = blockIdx.x;
    const int tid  = threadIdx.x;
    const int w    = tid >> 6;       // wave = head
    const int lane = tid & 63;
    const int g    = lane >> 4;
    const int c0   = lane & 15;
    const bool gl  = (g & 1) != 0, gh = (g & 2) != 0;
    const int h    = w;

    // fragment loads: all contiguous 16B/lane, all independent -> one latency hit
    const bf16_t* hb = qkv + (long)b * 24576 + h * 6144;
    bf16x8 qfr[4], ka[4], va[2][2];
    #pragma unroll
    for (int t = 0; t < 4; ++t)
        qfr[t] = *(const bf16x8*)(hb + (16 * t + c0) * 32 + 8 * g);
    #pragma unroll
    for (int kt = 0; kt < 4; ++kt)
        ka[kt] = *(const bf16x8*)(hb + 2048 + (16 * kt + c0) * 32 + 8 * g);
    #pragma unroll
    for (int fi = 0; fi < 2; ++fi)
        #pragma unroll
        for (int kt = 0; kt < 2; ++kt)
            va[fi][kt] = *(const bf16x8*)(hb + 4096 + (16 * fi + c0) * 64 + 32 * kt + 8 * g);

    // attention per 16-q-tile (r6-verified)
    const float* mrow = maskg + (long)(b % nW) * 2401;
    #pragma unroll
    for (int nt = 0; nt < 4; ++nt) {
        f32x4 s[4];
        #pragma unroll
        for (int kt = 0; kt < 4; ++kt) s[kt] = {0.f, 0.f, 0.f, 0.f};
        #pragma unroll
        for (int kt = 0; kt < 4; ++kt)
            s[kt] = MFMA16(ka[kt], qfr[nt], s[kt]);   // D[kv][q]

        {
            int q  = 16 * nt + c0;
            int qm = q < 49 ? q : 48;
            const float* mr = mrow + qm * 49;
            f32x4u m0 = *(const f32x4u*)(mr + 4 * g);
            f32x4u m1 = *(const f32x4u*)(mr + 16 + 4 * g);
            f32x4u m2 = *(const f32x4u*)(mr + 32 + 4 * g);
            float m48 = mr[48];
            #pragma unroll
            for (int r = 0; r < 4; ++r) {
                s[0][r] += m0[r]; s[1][r] += m1[r]; s[2][r] += m2[r];
            }
            s[3][0] = (g == 0) ? s[3][0] + m48 : -1e30f;
            s[3][1] = -1e30f; s[3][2] = -1e30f; s[3][3] = -1e30f;
        }

        float mx = -1e30f;
        #pragma unroll
        for (int kt = 0; kt < 4; ++kt)
            #pragma unroll
            for (int r = 0; r < 4; ++r) mx = fmaxf(mx, s[kt][r]);
        mx = fmaxf(mx, __shfl_xor(mx, 16));
        mx = fmaxf(mx, __shfl_xor(mx, 32));

        float sum = 0.f;
        u32 wd[8];
        #pragma unroll
        for (int kt = 0; kt < 4; ++kt) {
            float e0 = __expf(s[kt][0] - mx), e1 = __expf(s[kt][1] - mx);
            float e2 = __expf(s[kt][2] - mx), e3 = __expf(s[kt][3] - mx);
            sum += (e0 + e1) + (e2 + e3);
            wd[2 * kt]     = pack2(e0, e1);
            wd[2 * kt + 1] = pack2(e2, e3);
        }
        sum += __shfl_xor(sum, 16);
        sum += __shfl_xor(sum, 32);
        float inv = 1.f / sum;

        bf16x8 pa0 = redist4(wd[0], wd[1], wd[2], wd[3], gl, gh);
        bf16x8 pa1 = redist4(wd[4], wd[5], wd[6], wd[7], gl, gh);

        f32x4 oo[2];
        oo[0] = {0.f, 0.f, 0.f, 0.f}; oo[1] = {0.f, 0.f, 0.f, 0.f};
        oo[0] = MFMA16(va[0][0], pa0, oo[0]);
        oo[0] = MFMA16(va[0][1], pa1, oo[0]);
        oo[1] = MFMA16(va[1][0], pa0, oo[1]);
        oo[1] = MFMA16(va[1][1], pa1, oo[1]);

        int q = 16 * nt + c0;
        #pragma unroll
        for (int dt = 0; dt < 2; ++dt) {
            bf16x4 t;
            t[0] = (bf16_t)(oo[dt][0] * inv); t[1] = (bf16_t)(oo[dt][1] * inv);
            t[2] = (bf16_t)(oo[dt][2] * inv); t[3] = (bf16_t)(oo[dt][3] * inv);
            st4(as_, q, (32 * h + 16 * dt + 4 * g) * 2, t);
        }
    }

    // prefetch proj weights + bias across the barrier
    bf16x8 pwf[4][2];
    #pragma unroll
    for (int ks = 0; ks < 4; ++ks) {
        pwf[ks][0] = ldw<USEB>(pwg, wpb, (32 * w + c0) * 128 + 32 * ks + 8 * g);
        pwf[ks][1] = ldw<USEB>(pwg, wpb, (32 * w + 16 + c0) * 128 + 32 * ks + 8 * g);
    }
    float4 pb0 = *(const float4*)(pbg + 32 * w + 4 * g);
    float4 pb1 = *(const float4*)(pbg + 32 * w + 16 + 4 * g);
    __syncthreads();

    // proj GEMM: D[col][tok]
    {
        f32x4 acc[2][4];
        #pragma unroll
        for (int nt = 0; nt < 2; ++nt)
            #pragma unroll
            for (int mt = 0; mt < 4; ++mt) acc[nt][mt] = {0.f, 0.f, 0.f, 0.f};
        #pragma unroll
        for (int ks = 0; ks < 4; ++ks) {
            #pragma unroll
            for (int mt = 0; mt < 4; ++mt) {
                bf16x8 af = ld8(as_, 16 * mt + c0, (32 * ks + 8 * g) * 2);
                acc[0][mt] = MFMA16(pwf[ks][0], af, acc[0][mt]);
                acc[1][mt] = MFMA16(pwf[ks][1], af, acc[1][mt]);
            }
        }
        float* ob = outg + (long)b * 6272;
        #pragma unroll
        for (int nt = 0; nt < 2; ++nt) {
            float4 pb = nt ? pb1 : pb0;
            #pragma unroll
            for (int mt = 0; mt < 4; ++mt) {
                int tok = 16 * mt + c0;
                if (tok < 49) {
                    float4 t;
                    t.x = acc[nt][mt][0] + pb.x;
                    t.y = acc[nt][mt][1] + pb.y;
                    t.z = acc[nt][mt][2] + pb.z;
                    t.w = acc[nt][mt][3] + pb.w;
                    *(float4*)(ob + tok * 128 + 32 * w + 16 * nt + 4 * g) = t;
                }
            }
        }
    }
}

// ===================== FUSED FALLBACK (r6, 67.4 µs, unchanged) =====================

template<int USEB>
__device__ __forceinline__ void qk_pass_f(
    const char* xs, const float* __restrict__ wf, const bf16_t* __restrict__ wb,
    int rowbase, const float* __restrict__ biasp, float scale,
    int g, int c0, bool gl, bool gh, bf16x8 out[4])
{
    f32x4 acc[2][4];
    #pragma unroll
    for (int d = 0; d < 2; ++d)
        #pragma unroll
        for (int mt = 0; mt < 4; ++mt) acc[d][mt] = {0.f, 0.f, 0.f, 0.f};
    #pragma unroll
    for (int ks = 0; ks < 4; ++ks) {
        bf16x8 w0 = ldw<USEB>(wf, wb, (rowbase + c0) * 128 + 32 * ks + 8 * g);
        bf16x8 w1 = ldw<USEB>(wf, wb, (rowbase + 16 + c0) * 128 + 32 * ks + 8 * g);
        #pragma unroll
        for (int mt = 0; mt < 4; ++mt) {
            bf16x8 xf = ld8(xs, 16 * mt + c0, (32 * ks + 8 * g) * 2);
            acc[0][mt] = MFMA16(w0, xf, acc[0][mt]);
            acc[1][mt] = MFMA16(w1, xf, acc[1][mt]);
        }
    }
    float4 b0 = *(const float4*)(biasp + rowbase + 4 * g);
    float4 b1 = *(const float4*)(biasp + rowbase + 16 + 4 * g);
    #pragma unroll
    for (int t = 0; t < 4; ++t) {
        out[t] = redist4(
            pack2((acc[0][t][0] + b0.x) * scale, (acc[0][t][1] + b0.y) * scale),
            pack2((acc[0][t][2] + b0.z) * scale, (acc[0][t][3] + b0.w) * scale),
            pack2((acc[1][t][0] + b1.x) * scale, (acc[1][t][1] + b1.y) * scale),
            pack2((acc[1][t][2] + b1.z) * scale, (acc[1][t][3] + b1.w) * scale),
            gl, gh);
    }
}

template<int USEB>
__global__ __launch_bounds__(256, 4) void winattn_kernel(
    const float* __restrict__ xg, const float* __restrict__ maskg,
    const float* __restrict__ qwg, const float* __restrict__ qbg,
    const float* __restrict__ pwg, const float* __restrict__ pbg,
    const bf16_t* __restrict__ wqb, const bf16_t* __restrict__ wpb,
    const int nW, float* __restrict__ outg)
{
    __shared__ char xs[17408];

    const int b    = blockIdx.x;
    const int tid  = threadIdx.x;
    const int w    = tid >> 6;
    const int lane = tid & 63;
    const int g    = lane >> 4;
    const int c0   = lane & 15;
    const bool gl  = (g & 1) != 0, gh = (g & 2) != 0;
    const int h    = w;

    {
        const float4* xb = (const float4*)(xg + (long)b * 6272);
        #pragma unroll
        for (int it = 0; it < 7; ++it) {
            int i = tid + it * 256;
            if (i < 1568) {
                float4 f = xb[i];
                int row = i >> 5, colb = (i & 31) << 3;
                bf16x4 hq;
                hq[0] = (bf16_t)f.x; hq[1] = (bf16_t)f.y; hq[2] = (bf16_t)f.z; hq[3] = (bf16_t)f.w;
                st4(xs, row, colb, hq);
            }
        }
        #pragma unroll
        for (int it = 0; it < 4; ++it) {
            int i = tid + it * 256;
            if (i < 960) {
                int row = 49 + (i >> 6), byteo = (i & 63) << 2;
                *(u32*)(xs + row * ROWB + byteo) = 0u;
            }
        }
    }
    __syncthreads();

    const float qs = 0.17677669529663687f;
    bf16x8 qfr[4], ka[4];
    qk_pass_f<USEB>(xs, qwg, wqb, 32 * h,       qbg, qs,  g, c0, gl, gh, qfr);
    qk_pass_f<USEB>(xs, qwg, wqb, 128 + 32 * h, qbg, 1.f, g, c0, gl, gh, ka);

    bf16x8 va[2][2];
    {
        const int rb = 256 + 32 * h;
        f32x4 acc[4][2];
        #pragma unroll
        for (int mt = 0; mt < 4; ++mt)
            #pragma unroll
            for (int d = 0; d < 2; ++d) acc[mt][d] = {0.f, 0.f, 0.f, 0.f};
        #pragma unroll
        for (int ks = 0; ks < 4; ++ks) {
            bf16x8 w0 = ldw<USEB>(qwg, wqb, (rb + c0) * 128 + 32 * ks + 8 * g);
            bf16x8 w1 = ldw<USEB>(qwg, wqb, (rb + 16 + c0) * 128 + 32 * ks + 8 * g);
            #pragma unroll
            for (int mt = 0; mt < 4; ++mt) {
                bf16x8 xf = ld8(xs, 16 * mt + c0, (32 * ks + 8 * g) * 2);
                acc[mt][0] = MFMA16(xf, w0, acc[mt][0]);
                acc[mt][1] = MFMA16(xf, w1, acc[mt][1]);
            }
        }
        float vb0 = qbg[rb + c0];
        float vb1 = qbg[rb + 16 + c0];
        #pragma unroll
        for (int kt = 0; kt < 2; ++kt) {
            va[0][kt] = redist4(
                pack2(acc[2 * kt][0][0] + vb0, acc[2 * kt][0][1] + vb0),
                pack2(acc[2 * kt][0][2] + vb0, acc[2 * kt][0][3] + vb0),
                pack2(acc[2 * kt + 1][0][0] + vb0, acc[2 * kt + 1][0][1] + vb0),
                pack2(acc[2 * kt + 1][0][2] + vb0, acc[2 * kt + 1][0][3] + vb0),
                gl, gh);
            va[1][kt] = redist4(
                pack2(acc[2 * kt][1][0] + vb1, acc[2 * kt][1][1] + vb1),
                pack2(acc[2 * kt][1][2] + vb1, acc[2 * kt][1][3] + vb1),
                pack2(acc[2 * kt + 1][1][0] + vb1, acc[2 * kt + 1][1][1] + vb1),
                pack2(acc[2 * kt + 1][1][2] + vb1, acc[2 * kt + 1][1][3] + vb1),
                gl, gh);
        }
    }
    __syncthreads();

    const float* mrow = maskg + (long)(b % nW) * 2401;
    #pragma unroll
    for (int nt = 0; nt < 4; ++nt) {
        f32x4 s[4];
        #pragma unroll
        for (int kt = 0; kt < 4; ++kt) s[kt] = {0.f, 0.f, 0.f, 0.f};
        #pragma unroll
        for (int kt = 0; kt < 4; ++kt)
            s[kt] = MFMA16(ka[kt], qfr[nt], s[kt]);

        {
            int q  = 16 * nt + c0;
            int qm = q < 49 ? q : 48;
            const float* mr = mrow + qm * 49;
            f32x4u m0 = *(const f32x4u*)(mr + 4 * g);
            f32x4u m1 = *(const f32x4u*)(mr + 16 + 4 * g);
            f32x4u m2 = *(const f32x4u*)(mr + 32 + 4 * g);
            float m48 = mr[48];
            #pragma unroll
            for (int r = 0; r < 4; ++r) {
                s[0][r] += m0[r]; s[1][r] += m1[r]; s[2][r] += m2[r];
            }
            s[3][0] = (g == 0) ? s[3][0] + m48 : -1e30f;
            s[3][1] = -1e30f; s[3][2] = -1e30f; s[3][3] = -1e30f;
        }

        float mx = -1e30f;
        #pragma unroll
        for (int kt = 0; kt < 4; ++kt)
            #pragma unroll
            for (int r = 0; r < 4; ++r) mx = fmaxf(mx, s[kt][r]);
        mx = fmaxf(mx, __shfl_xor(mx, 16));
        mx = fmaxf(mx, __shfl_xor(mx, 32));

        float sum = 0.f;
        u32 wd[8];
        #pragma unroll
        for (int kt = 0; kt < 4; ++kt) {
            float e0 = __expf(s[kt][0] - mx), e1 = __expf(s[kt][1] - mx);
            float e2 = __expf(s[kt][2] - mx), e3 = __expf(s[kt][3] - mx);
            sum += (e0 + e1) + (e2 + e3);
            wd[2 * kt]     = pack2(e0, e1);
            wd[2 * kt + 1] = pack2(e2, e3);
        }
        sum += __shfl_xor(sum, 16);
        sum += __shfl_xor(sum, 32);
        float inv = 1.f / sum;

        bf16x8 pa0 = redist4(wd[0], wd[1], wd[2], wd[3], gl, gh);
        bf16x8 pa1 = redist4(wd[4], wd[5], wd[6], wd[7], gl, gh);

        f32x4 oo[2];
        oo[0] = {0.f, 0.f, 0.f, 0.f}; oo[1] = {0.f, 0.f, 0.f, 0.f};
        oo[0] = MFMA16(va[0][0], pa0, oo[0]);
        oo[0] = MFMA16(va[0][1], pa1, oo[0]);
        oo[1] = MFMA16(va[1][0], pa0, oo[1]);
        oo[1] = MFMA16(va[1][1], pa1, oo[1]);

        int q = 16 * nt + c0;
        #pragma unroll
        for (int dt = 0; dt < 2; ++dt) {
            bf16x4 t;
            t[0] = (bf16_t)(oo[dt][0] * inv); t[1] = (bf16_t)(oo[dt][1] * inv);
            t[2] = (bf16_t)(oo[dt][2] * inv); t[3] = (bf16_t)(oo[dt][3] * inv);
            st4(xs, q, (32 * h + 16 * dt + 4 * g) * 2, t);
        }
    }

    bf16x8 pwf[4][2];
    #pragma unroll
    for (int ks = 0; ks < 4; ++ks) {
        pwf[ks][0] = ldw<USEB>(pwg, wpb, (32 * w + c0) * 128 + 32 * ks + 8 * g);
        pwf[ks][1] = ldw<USEB>(pwg, wpb, (32 * w + 16 + c0) * 128 + 32 * ks + 8 * g);
    }
    float4 pb0 = *(const float4*)(pbg + 32 * w + 4 * g);
    float4 pb1 = *(const float4*)(pbg + 32 * w + 16 + 4 * g);
    __syncthreads();

    {
        f32x4 acc[2][4];
        #pragma unroll
        for (int nt = 0; nt < 2; ++nt)
            #pragma unroll
            for (int mt = 0; mt < 4; ++mt) acc[nt][mt] = {0.f, 0.f, 0.f, 0.f};
        #pragma unroll
        for (int ks = 0; ks < 4; ++ks) {
            #pragma unroll
            for (int mt = 0; mt < 4; ++mt) {
                bf16x8 af = ld8(xs, 16 * mt + c0, (32 * ks + 8 * g) * 2);
                acc[0][mt] = MFMA16(pwf[ks][0], af, acc[0][mt]);
                acc[1][mt] = MFMA16(pwf[ks][1], af, acc[1][mt]);
            }
        }
        float* ob = outg + (long)b * 6272;
        #pragma unroll
        for (int nt = 0; nt < 2; ++nt) {
            float4 pb = nt ? pb1 : pb0;
            #pragma unroll
            for (int mt = 0; mt < 4; ++mt) {
                int tok = 16 * mt + c0;
                if (tok < 49) {
                    float4 t;
                    t.x = acc[nt][mt][0] + pb.x;
                    t.y = acc[nt][mt][1] + pb.y;
                    t.z = acc[nt][mt][2] + pb.z;
                    t.w = acc[nt][mt][3] + pb.w;
                    *(float4*)(ob + tok * 128 + 32 * w + 16 * nt + 4 * g) = t;
                }
            }
        }
    }
}

extern "C" void kernel_launch(void* const* d_in, const int* in_sizes, int n_in,
                              void* d_out, int out_size, void* d_ws, size_t ws_size,
                              hipStream_t stream) {
    const float* xg  = (const float*)d_in[0];
    const float* mg  = (const float*)d_in[1];
    const float* qwg = (const float*)d_in[2];
    const float* qbg = (const float*)d_in[3];
    const float* pwg = (const float*)d_in[4];
    const float* pbg = (const float*)d_in[5];
    float* outg = (float*)d_out;

    const int B  = in_sizes[0] / (49 * 128);   // 2048
    const int nW = in_sizes[1] / (49 * 49);    // 64

    const size_t QKV_EL    = (size_t)B * 24576;          // bf16 elements
    const size_t NEED_SPLIT = QKV_EL * 2 + 131072;       // + bf16 weights

    if (d_ws != nullptr && ws_size >= NEED_SPLIT) {
        bf16_t* qkvws = (bf16_t*)d_ws;
        bf16_t* wqb   = qkvws + QKV_EL;
        bf16_t* wpb   = wqb + 49152;
        wconv_kernel<<<64, 256, 0, stream>>>(qwg, pwg, wqb);
        qkv_kernel<1><<<B, 256, 0, stream>>>(xg, qwg, qbg, wqb, qkvws);
        attn_kernel<1><<<B, 256, 0, stream>>>(qkvws, mg, pwg, pbg, wpb, nW, outg);
    } else if (d_ws != nullptr && ws_size >= 131072) {
        bf16_t* wqb = (bf16_t*)d_ws;
        bf16_t* wpb = wqb + 49152;
        wconv_kernel<<<64, 256, 0, stream>>>(qwg, pwg, wqb);
        winattn_kernel<1><<<B, 256, 0, stream>>>(
            xg, mg, qwg, qbg, pwg, pbg, wqb, wpb, nW, outg);
    } else {
        winattn_kernel<0><<<B, 256, 0, stream>>>(
            xg, mg, qwg, qbg, pwg, pbg, nullptr, nullptr, nW, outg);
    }
}

// Round 9
// 93.336 us; speedup vs baseline: 1.3918x; 1.3918x over previous
//
#include <hip/hip_runtime.h>

typedef __bf16 bf16_t;
typedef __bf16 bf16x2 __attribute__((ext_vector_type(2)));
typedef __bf16 bf16x4 __attribute__((ext_vector_type(4)));
typedef __bf16 bf16x8 __attribute__((ext_vector_type(8)));
typedef float  f32x4  __attribute__((ext_vector_type(4)));
typedef float  f32x4u __attribute__((ext_vector_type(4), aligned(4)));
typedef unsigned int u32;

#define MFMA16(a, b, c) __builtin_amdgcn_mfma_f32_16x16x32_bf16((a), (b), (c), 0, 0, 0)

#define ROWB 272   // x/att tile row stride bytes (+16B/row stagger -> 2-way, free)

// Fragment conventions for v_mfma_f32_16x16x32_bf16, D = A*B (verified r0-r8):
//  A (MxK): lane holds A[c0][8g+i], i=0..7
//  B (KxN): lane holds B[8g+i][c0]
//  D (MxN): lane reg r holds D[4g+r][c0]

union W8 { u32 u[4]; bf16x8 v; };

__device__ __forceinline__ u32 pack2(float a, float b) {
    union { bf16x2 h; u32 u; } c;
    c.h[0] = (bf16_t)a; c.h[1] = (bf16_t)b;
    return c.u;
}

__device__ __forceinline__ void st4(char* base, int row, int byteoff, bf16x4 v) {
    *(bf16x4*)(base + row * ROWB + byteoff) = v;
}
__device__ __forceinline__ bf16x8 ld8(const char* base, int row, int byteoff) {
    return *(const bf16x8*)(base + row * ROWB + byteoff);
}
// stage one float4 (covers x[i>>5][(i&31)*4 ..+3]) into the bf16 tile
__device__ __forceinline__ void stx(char* buf, int i, float4 f) {
    bf16x4 hq;
    hq[0] = (bf16_t)f.x; hq[1] = (bf16_t)f.y; hq[2] = (bf16_t)f.z; hq[3] = (bf16_t)f.w;
    st4(buf, i >> 5, (i & 31) << 3, hq);
}

// D-layout -> A/B-frag redistribution within each 4-lane c0-column (verified r3-r8).
__device__ __forceinline__ bf16x8 redist4(u32 w0, u32 w1, u32 w2, u32 w3,
                                          bool gl, bool gh) {
    u32 wd[4] = {w0, w1, w2, w3};
    u32 X[4], Y[4], Z[4];
    #pragma unroll
    for (int j = 0; j < 4; ++j) X[j] = __shfl_xor(wd[j], 16);
    #pragma unroll
    for (int j = 0; j < 4; ++j) Y[j] = __shfl_xor(wd[j], 32);
    #pragma unroll
    for (int j = 0; j < 4; ++j) Z[j] = __shfl_xor(X[j], 32);
    W8 u;
    #pragma unroll
    for (int t = 0; t < 4; ++t) {
        int j0 = t & 1;
        int j1 = j0 + 2;
        u32 lo, hi;
        if (t < 2) { lo = gl ? Z[j0] : wd[j0]; hi = gl ? X[j1] : Y[j1]; }
        else       { lo = gl ? Y[j0] : X[j0];  hi = gl ? wd[j1] : Z[j1]; }
        u.u[t] = gh ? hi : lo;
    }
    return u.v;
}

__global__ void wconv_kernel(const float* __restrict__ qw, const float* __restrict__ pw,
                             bf16_t* __restrict__ o) {
    int i = (blockIdx.x * 256 + threadIdx.x) * 4;   // 64*256*4 = 65536
    const float* src = (i < 49152) ? (qw + i) : (pw + (i - 49152));
    float4 f = *(const float4*)src;
    bf16x4 h;
    h[0] = (bf16_t)f.x; h[1] = (bf16_t)f.y; h[2] = (bf16_t)f.z; h[3] = (bf16_t)f.w;
    *(bf16x4*)(o + i) = h;
}

// ============== MULTI-WINDOW PERSISTENT-WEIGHT KERNEL ==============
// 512 threads (8 waves), each block runs WPB windows.
// LDS 76800 B: xbuf [64][136] bf16 (x then att) @0; per head h (7424 el @17408):
//   q[64][40] @0, k[64][40] @2560, vT[32][72] @5120.
// Wave roles (r3-verified): QKV: wave w owns q/k rows 32w..+31 (w<4: q, else k)
//   + v rows 256+16w..+15. Attention: head w>>1, q-half w&1. Proj: cols 16w..+15.
__global__ __launch_bounds__(512, 4) void mwin_kernel(
    const float* __restrict__ xg, const float* __restrict__ maskg,
    const bf16_t* __restrict__ wqb, const float* __restrict__ qbg,
    const bf16_t* __restrict__ wpb, const float* __restrict__ pbg,
    const int nW, const int WPB, const int Btot, float* __restrict__ outg)
{
    extern __shared__ char smem[];
    char*   xbuf  = smem;                      // [64][136] bf16: x then att
    bf16_t* heads = (bf16_t*)(smem + 17408);

    const int tid  = threadIdx.x;
    const int w    = tid >> 6;
    const int lane = tid & 63;
    const int g    = lane >> 4;
    const int c0   = lane & 15;
    const bool gl  = (g & 1) != 0, gh = (g & 2) != 0;
    const float qs = 0.17677669529663687f;     // 32^-0.5

    // persistent q/k weight fragments (loaded ONCE for all WPB windows)
    const int oqk = 32 * w;
    bf16x8 wqk[2][4];
    #pragma unroll
    for (int nt = 0; nt < 2; ++nt)
        #pragma unroll
        for (int ks = 0; ks < 4; ++ks)
            wqk[nt][ks] = *(const bf16x8*)(wqb + (oqk + 16*nt + c0)*128 + 32*ks + 8*g);
    float4 bqk[2];
    bqk[0] = *(const float4*)(qbg + oqk + 4*g);
    bqk[1] = *(const float4*)(qbg + oqk + 16 + 4*g);
    const int   ov   = 256 + 16 * w;
    const float bv   = qbg[ov + c0];
    const float qmul = (w < 4) ? qs : 1.f;

    bf16_t* qkdst = heads + (w & 3) * 7424 + (w < 4 ? 0 : 2560);
    bf16_t* vdst  = heads + (w >> 1) * 7424 + 5120 + (16*(w & 1) + c0) * 72;

    const int h = w >> 1, qh2 = w & 1;
    const bf16_t* qls = heads + h * 7424;
    const bf16_t* kls = qls + 2560;
    const bf16_t* vls = qls + 5120;

    const long b0 = (long)blockIdx.x * WPB;
    if (b0 >= Btot) return;

    // prologue: zero pad rows 49..63 once; stage window b0
    for (int i = tid; i < 960; i += 512) {
        int row = 49 + (i >> 6), byteo = (i & 63) << 2;
        *(u32*)(xbuf + row * ROWB + byteo) = 0u;
    }
    {
        const float4* xb = (const float4*)(xg + b0 * 6272);
        float4 f0 = xb[tid], f1 = xb[tid + 512], f2 = xb[tid + 1024];
        stx(xbuf, tid, f0); stx(xbuf, tid + 512, f1); stx(xbuf, tid + 1024, f2);
        if (tid < 32) { float4 f3 = xb[tid + 1536]; stx(xbuf, tid + 1536, f3); }
    }
    __syncthreads();

    for (int j = 0; j < WPB; ++j) {
        const long b = b0 + j;

        // ---------- ph1: QKV (weights in regs / L2-hot) ----------
        {
            f32x4 aqk[2][4];
            #pragma unroll
            for (int nt = 0; nt < 2; ++nt)
                #pragma unroll
                for (int mt = 0; mt < 4; ++mt) aqk[nt][mt] = {0.f, 0.f, 0.f, 0.f};
            #pragma unroll
            for (int ks = 0; ks < 4; ++ks)
                #pragma unroll
                for (int mt = 0; mt < 4; ++mt) {
                    bf16x8 xf = ld8(xbuf, 16*mt + c0, (32*ks + 8*g) * 2);
                    aqk[0][mt] = MFMA16(wqk[0][ks], xf, aqk[0][mt]);   // D[o][tok]
                    aqk[1][mt] = MFMA16(wqk[1][ks], xf, aqk[1][mt]);
                }
            #pragma unroll
            for (int nt = 0; nt < 2; ++nt) {
                int dh0 = 16*nt + 4*g;
                #pragma unroll
                for (int mt = 0; mt < 4; ++mt) {
                    int tok = 16*mt + c0;
                    bf16x4 tv;
                    tv[0] = (bf16_t)((aqk[nt][mt][0] + bqk[nt].x) * qmul);
                    tv[1] = (bf16_t)((aqk[nt][mt][1] + bqk[nt].y) * qmul);
                    tv[2] = (bf16_t)((aqk[nt][mt][2] + bqk[nt].z) * qmul);
                    tv[3] = (bf16_t)((aqk[nt][mt][3] + bqk[nt].w) * qmul);
                    *(bf16x4*)(qkdst + tok*40 + dh0) = tv;             // q/k[tok][dh]
                }
            }
            // v pass (weights reloaded per window; bf16 ws, L2-hot)
            f32x4 av[4];
            #pragma unroll
            for (int mt = 0; mt < 4; ++mt) av[mt] = {0.f, 0.f, 0.f, 0.f};
            #pragma unroll
            for (int ks = 0; ks < 4; ++ks) {
                bf16x8 wvk = *(const bf16x8*)(wqb + (ov + c0)*128 + 32*ks + 8*g);
                #pragma unroll
                for (int mt = 0; mt < 4; ++mt) {
                    bf16x8 xf = ld8(xbuf, 16*mt + c0, (32*ks + 8*g) * 2);
                    av[mt] = MFMA16(xf, wvk, av[mt]);                  // D[tok][o]
                }
            }
            #pragma unroll
            for (int mt = 0; mt < 4; ++mt) {
                bf16x4 tv;
                tv[0] = (bf16_t)(av[mt][0] + bv);
                tv[1] = (bf16_t)(av[mt][1] + bv);
                tv[2] = (bf16_t)(av[mt][2] + bv);
                tv[3] = (bf16_t)(av[mt][3] + bv);
                *(bf16x4*)(vdst + 16*mt + 4*g) = tv;                   // vT[dh][tok]
            }
        }
        __syncthreads();   // bar1: heads ready; x reads done

        // ---------- ph2: issue next-x loads (regs) + attention ----------
        float4 xr0, xr1, xr2, xr3;
        const bool pre = (j + 1 < WPB);
        if (pre) {
            const float4* xn = (const float4*)(xg + (b + 1) * 6272);
            xr0 = xn[tid]; xr1 = xn[tid + 512]; xr2 = xn[tid + 1024];
            if (tid < 32) xr3 = xn[tid + 1536];
        }
        {
            bf16x8 ka[4], qb2[2], va[2][2];
            #pragma unroll
            for (int kt = 0; kt < 4; ++kt)
                ka[kt] = *(const bf16x8*)(kls + (16*kt + c0)*40 + 8*g);
            #pragma unroll
            for (int nt = 0; nt < 2; ++nt)
                qb2[nt] = *(const bf16x8*)(qls + ((2*qh2 + nt)*16 + c0)*40 + 8*g);
            #pragma unroll
            for (int fi = 0; fi < 2; ++fi)
                #pragma unroll
                for (int kt = 0; kt < 2; ++kt)
                    va[fi][kt] = *(const bf16x8*)(vls + (16*fi + c0)*72 + 32*kt + 8*g);

            const float* mrow = maskg + (long)(b % nW) * 2401;
            #pragma unroll
            for (int nt = 0; nt < 2; ++nt) {
                f32x4 s[4];
                #pragma unroll
                for (int kt = 0; kt < 4; ++kt) s[kt] = {0.f, 0.f, 0.f, 0.f};
                #pragma unroll
                for (int kt = 0; kt < 4; ++kt)
                    s[kt] = MFMA16(ka[kt], qb2[nt], s[kt]);   // D[kv][q]

                int q  = (2*qh2 + nt)*16 + c0;
                int qm = q < 49 ? q : 48;
                const float* mr = mrow + qm * 49;
                f32x4u m0 = *(const f32x4u*)(mr + 4*g);
                f32x4u m1 = *(const f32x4u*)(mr + 16 + 4*g);
                f32x4u m2 = *(const f32x4u*)(mr + 32 + 4*g);
                float m48 = mr[48];
                #pragma unroll
                for (int r = 0; r < 4; ++r) {
                    s[0][r] += m0[r]; s[1][r] += m1[r]; s[2][r] += m2[r];
                }
                s[3][0] = (g == 0) ? s[3][0] + m48 : -1e30f;
                s[3][1] = -1e30f; s[3][2] = -1e30f; s[3][3] = -1e30f;

                float mx = -1e30f;
                #pragma unroll
                for (int kt = 0; kt < 4; ++kt)
                    #pragma unroll
                    for (int r = 0; r < 4; ++r) mx = fmaxf(mx, s[kt][r]);
                mx = fmaxf(mx, __shfl_xor(mx, 16));
                mx = fmaxf(mx, __shfl_xor(mx, 32));

                float sum = 0.f;
                u32 wd[8];
                #pragma unroll
                for (int kt = 0; kt < 4; ++kt) {
                    float e0 = __expf(s[kt][0] - mx), e1 = __expf(s[kt][1] - mx);
                    float e2 = __expf(s[kt][2] - mx), e3 = __expf(s[kt][3] - mx);
                    sum += (e0 + e1) + (e2 + e3);
                    wd[2*kt]     = pack2(e0, e1);
                    wd[2*kt + 1] = pack2(e2, e3);
                }
                sum += __shfl_xor(sum, 16);
                sum += __shfl_xor(sum, 32);
                float inv = 1.f / sum;

                bf16x8 pa0 = redist4(wd[0], wd[1], wd[2], wd[3], gl, gh);
                bf16x8 pa1 = redist4(wd[4], wd[5], wd[6], wd[7], gl, gh);

                f32x4 oo0 = {0.f, 0.f, 0.f, 0.f}, oo1 = {0.f, 0.f, 0.f, 0.f};
                oo0 = MFMA16(va[0][0], pa0, oo0);
                oo0 = MFMA16(va[0][1], pa1, oo0);   // D[dh 0-15][q]
                oo1 = MFMA16(va[1][0], pa0, oo1);
                oo1 = MFMA16(va[1][1], pa1, oo1);   // D[dh 16-31][q]

                bf16x4 t0, t1;
                t0[0] = (bf16_t)(oo0[0] * inv); t0[1] = (bf16_t)(oo0[1] * inv);
                t0[2] = (bf16_t)(oo0[2] * inv); t0[3] = (bf16_t)(oo0[3] * inv);
                t1[0] = (bf16_t)(oo1[0] * inv); t1[1] = (bf16_t)(oo1[1] * inv);
                t1[2] = (bf16_t)(oo1[2] * inv); t1[3] = (bf16_t)(oo1[3] * inv);
                st4(xbuf, q, (32*h + 4*g) * 2, t0);        // att[q][c]
                st4(xbuf, q, (32*h + 16 + 4*g) * 2, t1);
            }
        }
        __syncthreads();   // bar2: att ready; heads free for next window

        // ---------- ph3: proj (D[col][tok], cols 16w..+15) ----------
        {
            bf16x8 pwf[4];
            #pragma unroll
            for (int ks = 0; ks < 4; ++ks)
                pwf[ks] = *(const bf16x8*)(wpb + (16*w + c0)*128 + 32*ks + 8*g);
            float4 pb4 = *(const float4*)(pbg + 16*w + 4*g);
            f32x4 pacc[4];
            #pragma unroll
            for (int mt = 0; mt < 4; ++mt) pacc[mt] = {0.f, 0.f, 0.f, 0.f};
            #pragma unroll
            for (int ks = 0; ks < 4; ++ks)
                #pragma unroll
                for (int mt = 0; mt < 4; ++mt) {
                    bf16x8 af = ld8(xbuf, 16*mt + c0, (32*ks + 8*g) * 2);
                    pacc[mt] = MFMA16(pwf[ks], af, pacc[mt]);
                }
            float* ob = outg + b * 6272;
            #pragma unroll
            for (int mt = 0; mt < 4; ++mt) {
                int tok = 16*mt + c0;
                if (tok < 49) {
                    float4 t;
                    t.x = pacc[mt][0] + pb4.x;
                    t.y = pacc[mt][1] + pb4.y;
                    t.z = pacc[mt][2] + pb4.z;
                    t.w = pacc[mt][3] + pb4.w;
                    *(float4*)(ob + tok*128 + 16*w + 4*g) = t;
                }
            }
        }
        if (pre) {
            __syncthreads();   // bar3: att reads done -> staging may overwrite
            stx(xbuf, tid, xr0); stx(xbuf, tid + 512, xr1); stx(xbuf, tid + 1024, xr2);
            if (tid < 32) stx(xbuf, tid + 1536, xr3);
            __syncthreads();   // bar4: next x staged
        }
    }
}

// ============== FUSED FALLBACK (r6 structure, USEB=0, no ws needed) ==============
__device__ __forceinline__ bf16x8 ldwf(const float* __restrict__ wf, int idx) {
    float4 f0 = *(const float4*)(wf + idx);
    float4 f1 = *(const float4*)(wf + idx + 4);
    bf16x8 r;
    r[0] = (bf16_t)f0.x; r[1] = (bf16_t)f0.y; r[2] = (bf16_t)f0.z; r[3] = (bf16_t)f0.w;
    r[4] = (bf16_t)f1.x; r[5] = (bf16_t)f1.y; r[6] = (bf16_t)f1.z; r[7] = (bf16_t)f1.w;
    return r;
}

__device__ __forceinline__ void qk_pass_f(
    const char* xs, const float* __restrict__ wf,
    int rowbase, const float* __restrict__ biasp, float scale,
    int g, int c0, bool gl, bool gh, bf16x8 out[4])
{
    f32x4 acc[2][4];
    #pragma unroll
    for (int d = 0; d < 2; ++d)
        #pragma unroll
        for (int mt = 0; mt < 4; ++mt) acc[d][mt] = {0.f, 0.f, 0.f, 0.f};
    #pragma unroll
    for (int ks = 0; ks < 4; ++ks) {
        bf16x8 w0 = ldwf(wf, (rowbase + c0) * 128 + 32*ks + 8*g);
        bf16x8 w1 = ldwf(wf, (rowbase + 16 + c0) * 128 + 32*ks + 8*g);
        #pragma unroll
        for (int mt = 0; mt < 4; ++mt) {
            bf16x8 xf = ld8(xs, 16*mt + c0, (32*ks + 8*g) * 2);
            acc[0][mt] = MFMA16(w0, xf, acc[0][mt]);
            acc[1][mt] = MFMA16(w1, xf, acc[1][mt]);
        }
    }
    float4 b0 = *(const float4*)(biasp + rowbase + 4*g);
    float4 b1 = *(const float4*)(biasp + rowbase + 16 + 4*g);
    #pragma unroll
    for (int t = 0; t < 4; ++t) {
        out[t] = redist4(
            pack2((acc[0][t][0] + b0.x) * scale, (acc[0][t][1] + b0.y) * scale),
            pack2((acc[0][t][2] + b0.z) * scale, (acc[0][t][3] + b0.w) * scale),
            pack2((acc[1][t][0] + b1.x) * scale, (acc[1][t][1] + b1.y) * scale),
            pack2((acc[1][t][2] + b1.z) * scale, (acc[1][t][3] + b1.w) * scale),
            gl, gh);
    }
}

__global__ __launch_bounds__(256, 4) void winattn_fb(
    const float* __restrict__ xg, const float* __restrict__ maskg,
    const float* __restrict__ qwg, const float* __restrict__ qbg,
    const float* __restrict__ pwg, const float* __restrict__ pbg,
    const int nW, float* __restrict__ outg)
{
    __shared__ char xs[17408];
    const int b    = blockIdx.x;
    const int tid  = threadIdx.x;
    const int w    = tid >> 6;
    const int lane = tid & 63;
    const int g    = lane >> 4;
    const int c0   = lane & 15;
    const bool gl  = (g & 1) != 0, gh = (g & 2) != 0;
    const int h    = w;

    {
        const float4* xb = (const float4*)(xg + (long)b * 6272);
        #pragma unroll
        for (int it = 0; it < 7; ++it) {
            int i = tid + it * 256;
            if (i < 1568) { float4 f = xb[i]; stx(xs, i, f); }
        }
        #pragma unroll
        for (int it = 0; it < 4; ++it) {
            int i = tid + it * 256;
            if (i < 960) {
                int row = 49 + (i >> 6), byteo = (i & 63) << 2;
                *(u32*)(xs + row * ROWB + byteo) = 0u;
            }
        }
    }
    __syncthreads();

    const float qs = 0.17677669529663687f;
    bf16x8 qfr[4], ka[4];
    qk_pass_f(xs, qwg, 32*h,       qbg, qs,  g, c0, gl, gh, qfr);
    qk_pass_f(xs, qwg, 128 + 32*h, qbg, 1.f, g, c0, gl, gh, ka);

    bf16x8 va[2][2];
    {
        const int rb = 256 + 32*h;
        f32x4 acc[4][2];
        #pragma unroll
        for (int mt = 0; mt < 4; ++mt)
            #pragma unroll
            for (int d = 0; d < 2; ++d) acc[mt][d] = {0.f, 0.f, 0.f, 0.f};
        #pragma unroll
        for (int ks = 0; ks < 4; ++ks) {
            bf16x8 w0 = ldwf(qwg, (rb + c0) * 128 + 32*ks + 8*g);
            bf16x8 w1 = ldwf(qwg, (rb + 16 + c0) * 128 + 32*ks + 8*g);
            #pragma unroll
            for (int mt = 0; mt < 4; ++mt) {
                bf16x8 xf = ld8(xs, 16*mt + c0, (32*ks + 8*g) * 2);
                acc[mt][0] = MFMA16(xf, w0, acc[mt][0]);
                acc[mt][1] = MFMA16(xf, w1, acc[mt][1]);
            }
        }
        float vb0 = qbg[rb + c0];
        float vb1 = qbg[rb + 16 + c0];
        #pragma unroll
        for (int kt = 0; kt < 2; ++kt) {
            va[0][kt] = redist4(
                pack2(acc[2*kt][0][0] + vb0, acc[2*kt][0][1] + vb0),
                pack2(acc[2*kt][0][2] + vb0, acc[2*kt][0][3] + vb0),
                pack2(acc[2*kt+1][0][0] + vb0, acc[2*kt+1][0][1] + vb0),
                pack2(acc[2*kt+1][0][2] + vb0, acc[2*kt+1][0][3] + vb0),
                gl, gh);
            va[1][kt] = redist4(
                pack2(acc[2*kt][1][0] + vb1, acc[2*kt][1][1] + vb1),
                pack2(acc[2*kt][1][2] + vb1, acc[2*kt][1][3] + vb1),
                pack2(acc[2*kt+1][1][0] + vb1, acc[2*kt+1][1][1] + vb1),
                pack2(acc[2*kt+1][1][2] + vb1, acc[2*kt+1][1][3] + vb1),
                gl, gh);
        }
    }
    __syncthreads();

    const float* mrow = maskg + (long)(b % nW) * 2401;
    #pragma unroll
    for (int nt = 0; nt < 4; ++nt) {
        f32x4 s[4];
        #pragma unroll
        for (int kt = 0; kt < 4; ++kt) s[kt] = {0.f, 0.f, 0.f, 0.f};
        #pragma unroll
        for (int kt = 0; kt < 4; ++kt)
            s[kt] = MFMA16(ka[kt], qfr[nt], s[kt]);
        {
            int q  = 16*nt + c0;
            int qm = q < 49 ? q : 48;
            const float* mr = mrow + qm * 49;
            f32x4u m0 = *(const f32x4u*)(mr + 4*g);
            f32x4u m1 = *(const f32x4u*)(mr + 16 + 4*g);
            f32x4u m2 = *(const f32x4u*)(mr + 32 + 4*g);
            float m48 = mr[48];
            #pragma unroll
            for (int r = 0; r < 4; ++r) {
                s[0][r] += m0[r]; s[1][r] += m1[r]; s[2][r] += m2[r];
            }
            s[3][0] = (g == 0) ? s[3][0] + m48 : -1e30f;
            s[3][1] = -1e30f; s[3][2] = -1e30f; s[3][3] = -1e30f;
        }
        float mx = -1e30f;
        #pragma unroll
        for (int kt = 0; kt < 4; ++kt)
            #pragma unroll
            for (int r = 0; r < 4; ++r) mx = fmaxf(mx, s[kt][r]);
        mx = fmaxf(mx, __shfl_xor(mx, 16));
        mx = fmaxf(mx, __shfl_xor(mx, 32));
        float sum = 0.f;
        u32 wd[8];
        #pragma unroll
        for (int kt = 0; kt < 4; ++kt) {
            float e0 = __expf(s[kt][0] - mx), e1 = __expf(s[kt][1] - mx);
            float e2 = __expf(s[kt][2] - mx), e3 = __expf(s[kt][3] - mx);
            sum += (e0 + e1) + (e2 + e3);
            wd[2*kt]     = pack2(e0, e1);
            wd[2*kt + 1] = pack2(e2, e3);
        }
        sum += __shfl_xor(sum, 16);
        sum += __shfl_xor(sum, 32);
        float inv = 1.f / sum;

        bf16x8 pa0 = redist4(wd[0], wd[1], wd[2], wd[3], gl, gh);
        bf16x8 pa1 = redist4(wd[4], wd[5], wd[6], wd[7], gl, gh);

        f32x4 oo[2];
        oo[0] = {0.f, 0.f, 0.f, 0.f}; oo[1] = {0.f, 0.f, 0.f, 0.f};
        oo[0] = MFMA16(va[0][0], pa0, oo[0]);
        oo[0] = MFMA16(va[0][1], pa1, oo[0]);
        oo[1] = MFMA16(va[1][0], pa0, oo[1]);
        oo[1] = MFMA16(va[1][1], pa1, oo[1]);

        int q = 16*nt + c0;
        #pragma unroll
        for (int dt = 0; dt < 2; ++dt) {
            bf16x4 t;
            t[0] = (bf16_t)(oo[dt][0] * inv); t[1] = (bf16_t)(oo[dt][1] * inv);
            t[2] = (bf16_t)(oo[dt][2] * inv); t[3] = (bf16_t)(oo[dt][3] * inv);
            st4(xs, q, (32*h + 16*dt + 4*g) * 2, t);
        }
    }

    bf16x8 pwf[4][2];
    #pragma unroll
    for (int ks = 0; ks < 4; ++ks) {
        pwf[ks][0] = ldwf(pwg, (32*w + c0) * 128 + 32*ks + 8*g);
        pwf[ks][1] = ldwf(pwg, (32*w + 16 + c0) * 128 + 32*ks + 8*g);
    }
    float4 pb0 = *(const float4*)(pbg + 32*w + 4*g);
    float4 pb1 = *(const float4*)(pbg + 32*w + 16 + 4*g);
    __syncthreads();

    {
        f32x4 acc[2][4];
        #pragma unroll
        for (int nt = 0; nt < 2; ++nt)
            #pragma unroll
            for (int mt = 0; mt < 4; ++mt) acc[nt][mt] = {0.f, 0.f, 0.f, 0.f};
        #pragma unroll
        for (int ks = 0; ks < 4; ++ks) {
            #pragma unroll
            for (int mt = 0; mt < 4; ++mt) {
                bf16x8 af = ld8(xs, 16*mt + c0, (32*ks + 8*g) * 2);
                acc[0][mt] = MFMA16(pwf[ks][0], af, acc[0][mt]);
                acc[1][mt] = MFMA16(pwf[ks][1], af, acc[1][mt]);
            }
        }
        float* ob = outg + (long)b * 6272;
        #pragma unroll
        for (int nt = 0; nt < 2; ++nt) {
            float4 pb = nt ? pb1 : pb0;
            #pragma unroll
            for (int mt = 0; mt < 4; ++mt) {
                int tok = 16*mt + c0;
                if (tok < 49) {
                    float4 t;
                    t.x = acc[nt][mt][0] + pb.x;
                    t.y = acc[nt][mt][1] + pb.y;
                    t.z = acc[nt][mt][2] + pb.z;
                    t.w = acc[nt][mt][3] + pb.w;
                    *(float4*)(ob + tok*128 + 32*w + 16*nt + 4*g) = t;
                }
            }
        }
    }
}

extern "C" void kernel_launch(void* const* d_in, const int* in_sizes, int n_in,
                              void* d_out, int out_size, void* d_ws, size_t ws_size,
                              hipStream_t stream) {
    const float* xg  = (const float*)d_in[0];
    const float* mg  = (const float*)d_in[1];
    const float* qwg = (const float*)d_in[2];
    const float* qbg = (const float*)d_in[3];
    const float* pwg = (const float*)d_in[4];
    const float* pbg = (const float*)d_in[5];
    float* outg = (float*)d_out;

    const int B  = in_sizes[0] / (49 * 128);   // 2048
    const int nW = in_sizes[1] / (49 * 49);    // 64

    const int NBLK = 512;
    if (d_ws != nullptr && ws_size >= 131072 && (B % NBLK) == 0) {
        bf16_t* wqb = (bf16_t*)d_ws;          // [384][128] bf16
        bf16_t* wpb = wqb + 49152;            // [128][128] bf16
        wconv_kernel<<<64, 256, 0, stream>>>(qwg, pwg, wqb);
        (void)hipFuncSetAttribute((const void*)mwin_kernel,
                                  hipFuncAttributeMaxDynamicSharedMemorySize, 76800);
        const int WPB = B / NBLK;             // 4
        mwin_kernel<<<NBLK, 512, 76800, stream>>>(
            xg, mg, wqb, qbg, wpb, pbg, nW, WPB, B, outg);
    } else {
        winattn_fb<<<B, 256, 0, stream>>>(
            xg, mg, qwg, qbg, pwg, pbg, nW, outg);
    }
}

// Round 10
// 64.915 us; speedup vs baseline: 2.0011x; 1.4378x over previous
//
#include <hip/hip_runtime.h>

typedef __bf16 bf16_t;
typedef __bf16 bf16x2 __attribute__((ext_vector_type(2)));
typedef __bf16 bf16x4 __attribute__((ext_vector_type(4)));
typedef __bf16 bf16x8 __attribute__((ext_vector_type(8)));
typedef float  f32x4  __attribute__((ext_vector_type(4)));
typedef float  f32x4u __attribute__((ext_vector_type(4), aligned(4)));
typedef short  s16x4  __attribute__((ext_vector_type(4)));
typedef unsigned int u32;

#define MFMA32(a, b, c) __builtin_amdgcn_mfma_f32_16x16x32_bf16((a), (b), (c), 0, 0, 0)

// K=16 MFMA: v_mfma_f32_16x16x16_bf16. Fragment maps (CDNA canonical):
//   A: lane holds A[c0][4g+i], B: lane holds B[4g+i][c0], D: reg r -> D[4g+r][c0].
// KEY IDENTITY: a 16x16 D-tile is register-identical to a K=16 B-frag (r<->i),
// and to a K=16 A-frag of the transposed matrix. So Q/K/V/P produced in D-layout
// feed QK^T and PV with ZERO cross-lane ops.
union B4u { bf16x4 h; s16x4 s; };
__device__ __forceinline__ f32x4 MFMA16(bf16x4 a, bf16x4 b, f32x4 c) {
#if __has_builtin(__builtin_amdgcn_mfma_f32_16x16x16_bf16)
    return __builtin_amdgcn_mfma_f32_16x16x16_bf16(a, b, c, 0, 0, 0);
#elif __has_builtin(__builtin_amdgcn_mfma_f32_16x16x16bf16_1k)
    B4u ua, ub; ua.h = a; ub.h = b;
    return __builtin_amdgcn_mfma_f32_16x16x16bf16_1k(ua.s, ub.s, c, 0, 0, 0);
#else
    f32x4 d = c;
    asm volatile("v_mfma_f32_16x16x16_bf16 %0, %1, %2, %0"
                 : "+v"(d) : "v"(a), "v"(b));
    return d;
#endif
}

#define ROWB 272   // LDS tile row stride (natural +16B/row stagger -> 2-way, free)

__device__ __forceinline__ void st4(char* base, int row, int byteoff, bf16x4 v) {
    *(bf16x4*)(base + row * ROWB + byteoff) = v;
}
__device__ __forceinline__ bf16x8 ld8(const char* base, int row, int byteoff) {
    return *(const bf16x8*)(base + row * ROWB + byteoff);
}
__device__ __forceinline__ void stx(char* buf, int i, float4 f) {
    bf16x4 hq;
    hq[0] = (bf16_t)f.x; hq[1] = (bf16_t)f.y; hq[2] = (bf16_t)f.z; hq[3] = (bf16_t)f.w;
    st4(buf, i >> 5, (i & 31) << 3, hq);
}

__device__ __forceinline__ bf16x4 cvt4b(f32x4 v, float4 bias, float sc) {
    bf16x4 t;
    t[0] = (bf16_t)((v[0] + bias.x) * sc);
    t[1] = (bf16_t)((v[1] + bias.y) * sc);
    t[2] = (bf16_t)((v[2] + bias.z) * sc);
    t[3] = (bf16_t)((v[3] + bias.w) * sc);
    return t;
}
__device__ __forceinline__ bf16x4 cvt4s(f32x4 v, float bias) {
    bf16x4 t;
    t[0] = (bf16_t)(v[0] + bias);
    t[1] = (bf16_t)(v[1] + bias);
    t[2] = (bf16_t)(v[2] + bias);
    t[3] = (bf16_t)(v[3] + bias);
    return t;
}

__global__ void wconv_kernel(const float* __restrict__ qw, const float* __restrict__ pw,
                             bf16_t* __restrict__ o) {
    int i = (blockIdx.x * 256 + threadIdx.x) * 4;   // 64*256*4 = 65536
    const float* src = (i < 49152) ? (qw + i) : (pw + (i - 49152));
    float4 f = *(const float4*)src;
    bf16x4 h;
    h[0] = (bf16_t)f.x; h[1] = (bf16_t)f.y; h[2] = (bf16_t)f.z; h[3] = (bf16_t)f.w;
    *(bf16x4*)(o + i) = h;
}

template<int USEB>
__device__ __forceinline__ bf16x8 ldw(const float* __restrict__ wf,
                                      const bf16_t* __restrict__ wb, int idx) {
    if constexpr (USEB) {
        return *(const bf16x8*)(wb + idx);
    } else {
        float4 f0 = *(const float4*)(wf + idx);
        float4 f1 = *(const float4*)(wf + idx + 4);
        bf16x8 r;
        r[0] = (bf16_t)f0.x; r[1] = (bf16_t)f0.y; r[2] = (bf16_t)f0.z; r[3] = (bf16_t)f0.w;
        r[4] = (bf16_t)f1.x; r[5] = (bf16_t)f1.y; r[6] = (bf16_t)f1.z; r[7] = (bf16_t)f1.w;
        return r;
    }
}

// Fragment conventions for v_mfma_f32_16x16x32_bf16, D = A*B (verified r0-r9):
//  A (MxK): lane holds A[c0][8g+i], i=0..7
//  B (KxN): lane holds B[8g+i][c0]
//  D (MxN): lane reg r holds D[4g+r][c0]

template<int USEB>
__global__ __launch_bounds__(256, 2) void winattn_kernel(
    const float* __restrict__ xg, const float* __restrict__ maskg,
    const float* __restrict__ qwg, const float* __restrict__ qbg,
    const float* __restrict__ pwg, const float* __restrict__ pbg,
    const bf16_t* __restrict__ wqb, const bf16_t* __restrict__ wpb,
    const int nW, float* __restrict__ outg)
{
    __shared__ char xs[17408];   // x [64][136] bf16, later att (same geometry)

    const int b    = blockIdx.x;
    const int tid  = threadIdx.x;
    const int w    = tid >> 6;       // wave 0..3 == head
    const int lane = tid & 63;
    const int g    = lane >> 4;
    const int c0   = lane & 15;
    const int h    = w;

    // ---- stage x (49x128 f32 -> bf16 LDS); zero rows 49..63 ----
    {
        const float4* xb = (const float4*)(xg + (long)b * 6272);
        #pragma unroll
        for (int it = 0; it < 7; ++it) {
            int i = tid + it * 256;
            if (i < 1568) { float4 f = xb[i]; stx(xs, i, f); }
        }
        #pragma unroll
        for (int it = 0; it < 4; ++it) {
            int i = tid + it * 256;
            if (i < 960) {
                int row = 49 + (i >> 6), byteo = (i & 63) << 2;
                *(u32*)(xs + row * ROWB + byteo) = 0u;
            }
        }
    }
    __syncthreads();   // b1: x staged

    const float qs = 0.17677669529663687f;   // 32^-0.5

    // ---- Q pass: D[dh][tok] = Wq * x^T; keep D-tiles as bf16x4 (K=16 B-frags) ----
    bf16x4 qfr[2][4];    // [dt][qt]: lane holds q(tok=16qt+c0, ch=32h+16dt+4g+r)
    {
        f32x4 acc[2][4];
        #pragma unroll
        for (int d = 0; d < 2; ++d)
            #pragma unroll
            for (int mt = 0; mt < 4; ++mt) acc[d][mt] = {0.f, 0.f, 0.f, 0.f};
        #pragma unroll
        for (int ks = 0; ks < 4; ++ks) {
            bf16x8 w0 = ldw<USEB>(qwg, wqb, (32*h + c0) * 128 + 32*ks + 8*g);
            bf16x8 w1 = ldw<USEB>(qwg, wqb, (32*h + 16 + c0) * 128 + 32*ks + 8*g);
            #pragma unroll
            for (int mt = 0; mt < 4; ++mt) {
                bf16x8 xf = ld8(xs, 16*mt + c0, (32*ks + 8*g) * 2);
                acc[0][mt] = MFMA32(w0, xf, acc[0][mt]);
                acc[1][mt] = MFMA32(w1, xf, acc[1][mt]);
            }
        }
        float4 b0 = *(const float4*)(qbg + 32*h + 4*g);
        float4 b1 = *(const float4*)(qbg + 32*h + 16 + 4*g);
        #pragma unroll
        for (int qt = 0; qt < 4; ++qt) {
            qfr[0][qt] = cvt4b(acc[0][qt], b0, qs);
            qfr[1][qt] = cvt4b(acc[1][qt], b1, qs);
        }
    }

    // ---- K pass: D[dh][tok] = Wk * x^T; D-tiles are K=16 A-frags of K[kv][dh] ----
    bf16x4 kfr[4][2];    // [kt][dt]: lane holds k(tok=16kt+c0, ch=32h+16dt+4g+i)
    {
        f32x4 acc[2][4];
        #pragma unroll
        for (int d = 0; d < 2; ++d)
            #pragma unroll
            for (int mt = 0; mt < 4; ++mt) acc[d][mt] = {0.f, 0.f, 0.f, 0.f};
        #pragma unroll
        for (int ks = 0; ks < 4; ++ks) {
            bf16x8 w0 = ldw<USEB>(qwg, wqb, (128 + 32*h + c0) * 128 + 32*ks + 8*g);
            bf16x8 w1 = ldw<USEB>(qwg, wqb, (128 + 32*h + 16 + c0) * 128 + 32*ks + 8*g);
            #pragma unroll
            for (int mt = 0; mt < 4; ++mt) {
                bf16x8 xf = ld8(xs, 16*mt + c0, (32*ks + 8*g) * 2);
                acc[0][mt] = MFMA32(w0, xf, acc[0][mt]);
                acc[1][mt] = MFMA32(w1, xf, acc[1][mt]);
            }
        }
        float4 b0 = *(const float4*)(qbg + 128 + 32*h + 4*g);
        float4 b1 = *(const float4*)(qbg + 128 + 32*h + 16 + 4*g);
        #pragma unroll
        for (int kt = 0; kt < 4; ++kt) {
            kfr[kt][0] = cvt4b(acc[0][kt], b0, 1.f);
            kfr[kt][1] = cvt4b(acc[1][kt], b1, 1.f);
        }
    }

    // ---- V pass: D[tok][dh] = x * Wv^T; D-tiles are K=16 A-frags of vT[dh][kv] ----
    bf16x4 vfr[2][4];    // [dt][kt]: lane holds v(tok=16kt+4g+i, ch=32h+16dt+c0)
    {
        f32x4 acc[4][2];
        #pragma unroll
        for (int mt = 0; mt < 4; ++mt)
            #pragma unroll
            for (int d = 0; d < 2; ++d) acc[mt][d] = {0.f, 0.f, 0.f, 0.f};
        #pragma unroll
        for (int ks = 0; ks < 4; ++ks) {
            bf16x8 w0 = ldw<USEB>(qwg, wqb, (256 + 32*h + c0) * 128 + 32*ks + 8*g);
            bf16x8 w1 = ldw<USEB>(qwg, wqb, (256 + 32*h + 16 + c0) * 128 + 32*ks + 8*g);
            #pragma unroll
            for (int mt = 0; mt < 4; ++mt) {
                bf16x8 xf = ld8(xs, 16*mt + c0, (32*ks + 8*g) * 2);
                acc[mt][0] = MFMA32(xf, w0, acc[mt][0]);
                acc[mt][1] = MFMA32(xf, w1, acc[mt][1]);
            }
        }
        float vb0 = qbg[256 + 32*h + c0];
        float vb1 = qbg[256 + 32*h + 16 + c0];
        #pragma unroll
        for (int kt = 0; kt < 4; ++kt) {
            vfr[0][kt] = cvt4s(acc[kt][0], vb0);
            vfr[1][kt] = cvt4s(acc[kt][1], vb1);
        }
    }
    __syncthreads();   // b2: all x reads done -> att may overwrite region

    // ---- attention per 16-q-tile: all operands in registers, zero shuffles ----
    const float* mrow = maskg + (long)(b % nW) * 2401;
    #pragma unroll
    for (int qt = 0; qt < 4; ++qt) {
        // S^T[kv][q]: A = kfr (K[kv][dh]), B = qfr (Q^T[dh][q]); acc over dt
        f32x4 s[4];
        #pragma unroll
        for (int kt = 0; kt < 4; ++kt) s[kt] = {0.f, 0.f, 0.f, 0.f};
        #pragma unroll
        for (int kt = 0; kt < 4; ++kt) {
            s[kt] = MFMA16(kfr[kt][0], qfr[0][qt], s[kt]);
            s[kt] = MFMA16(kfr[kt][1], qfr[1][qt], s[kt]);
        }
        // s[kt] reg r: kv=16kt+4g+r, q=16qt+c0  (same indexing as verified r6)

        {
            int q  = 16*qt + c0;
            int qm = q < 49 ? q : 48;
            const float* mr = mrow + qm * 49;
            f32x4u m0 = *(const f32x4u*)(mr + 4*g);
            f32x4u m1 = *(const f32x4u*)(mr + 16 + 4*g);
            f32x4u m2 = *(const f32x4u*)(mr + 32 + 4*g);
            float m48 = mr[48];
            #pragma unroll
            for (int r = 0; r < 4; ++r) {
                s[0][r] += m0[r]; s[1][r] += m1[r]; s[2][r] += m2[r];
            }
            s[3][0] = (g == 0) ? s[3][0] + m48 : -1e30f;
            s[3][1] = -1e30f; s[3][2] = -1e30f; s[3][3] = -1e30f;
        }

        float mx = -1e30f;
        #pragma unroll
        for (int kt = 0; kt < 4; ++kt)
            #pragma unroll
            for (int r = 0; r < 4; ++r) mx = fmaxf(mx, s[kt][r]);
        mx = fmaxf(mx, __shfl_xor(mx, 16));
        mx = fmaxf(mx, __shfl_xor(mx, 32));

        float sum = 0.f;
        bf16x4 p[4];   // P^T D-layout == K=16 B-frag: zero-shuffle handoff to PV
        #pragma unroll
        for (int kt = 0; kt < 4; ++kt) {
            float e0 = __expf(s[kt][0] - mx), e1 = __expf(s[kt][1] - mx);
            float e2 = __expf(s[kt][2] - mx), e3 = __expf(s[kt][3] - mx);
            sum += (e0 + e1) + (e2 + e3);
            bf16x4 pk;
            pk[0] = (bf16_t)e0; pk[1] = (bf16_t)e1;
            pk[2] = (bf16_t)e2; pk[3] = (bf16_t)e3;
            p[kt] = pk;
        }
        sum += __shfl_xor(sum, 16);
        sum += __shfl_xor(sum, 32);
        float inv = 1.f / sum;   // uniform across the 4 lanes of each c0 column

        // PV: out^T[dh][q] = sum_kt vT_tile * P_tile
        f32x4 oo[2];
        oo[0] = {0.f, 0.f, 0.f, 0.f}; oo[1] = {0.f, 0.f, 0.f, 0.f};
        #pragma unroll
        for (int kt = 0; kt < 4; ++kt) {
            oo[0] = MFMA16(vfr[0][kt], p[kt], oo[0]);
            oo[1] = MFMA16(vfr[1][kt], p[kt], oo[1]);
        }
        int q = 16*qt + c0;
        #pragma unroll
        for (int dt = 0; dt < 2; ++dt) {
            bf16x4 t;
            t[0] = (bf16_t)(oo[dt][0] * inv); t[1] = (bf16_t)(oo[dt][1] * inv);
            t[2] = (bf16_t)(oo[dt][2] * inv); t[3] = (bf16_t)(oo[dt][3] * inv);
            st4(xs, q, (32*h + 16*dt + 4*g) * 2, t);   // att[q][c]
        }
    }

    // prefetch proj weights + bias so they're in flight across the barrier
    bf16x8 pwf[4][2];
    #pragma unroll
    for (int ks = 0; ks < 4; ++ks) {
        pwf[ks][0] = ldw<USEB>(pwg, wpb, (32*w + c0) * 128 + 32*ks + 8*g);
        pwf[ks][1] = ldw<USEB>(pwg, wpb, (32*w + 16 + c0) * 128 + 32*ks + 8*g);
    }
    float4 pb0 = *(const float4*)(pbg + 32*w + 4*g);
    float4 pb1 = *(const float4*)(pbg + 32*w + 16 + 4*g);
    __syncthreads();   // b3: att complete

    // ---- proj GEMM: D[col][tok] = Wp * att^T (16x16x32, verified) ----
    {
        f32x4 acc[2][4];
        #pragma unroll
        for (int nt = 0; nt < 2; ++nt)
            #pragma unroll
            for (int mt = 0; mt < 4; ++mt) acc[nt][mt] = {0.f, 0.f, 0.f, 0.f};
        #pragma unroll
        for (int ks = 0; ks < 4; ++ks) {
            #pragma unroll
            for (int mt = 0; mt < 4; ++mt) {
                bf16x8 af = ld8(xs, 16*mt + c0, (32*ks + 8*g) * 2);
                acc[0][mt] = MFMA32(pwf[ks][0], af, acc[0][mt]);
                acc[1][mt] = MFMA32(pwf[ks][1], af, acc[1][mt]);
            }
        }
        float* ob = outg + (long)b * 6272;
        #pragma unroll
        for (int nt = 0; nt < 2; ++nt) {
            float4 pb = nt ? pb1 : pb0;
            #pragma unroll
            for (int mt = 0; mt < 4; ++mt) {
                int tok = 16*mt + c0;
                if (tok < 49) {
                    float4 t;
                    t.x = acc[nt][mt][0] + pb.x;
                    t.y = acc[nt][mt][1] + pb.y;
                    t.z = acc[nt][mt][2] + pb.z;
                    t.w = acc[nt][mt][3] + pb.w;
                    *(float4*)(ob + tok*128 + 32*w + 16*nt + 4*g) = t;
                }
            }
        }
    }
}

extern "C" void kernel_launch(void* const* d_in, const int* in_sizes, int n_in,
                              void* d_out, int out_size, void* d_ws, size_t ws_size,
                              hipStream_t stream) {
    const float* xg  = (const float*)d_in[0];
    const float* mg  = (const float*)d_in[1];
    const float* qwg = (const float*)d_in[2];
    const float* qbg = (const float*)d_in[3];
    const float* pwg = (const float*)d_in[4];
    const float* pbg = (const float*)d_in[5];
    float* outg = (float*)d_out;

    const int B  = in_sizes[0] / (49 * 128);   // 2048
    const int nW = in_sizes[1] / (49 * 49);    // 64

    if (d_ws != nullptr && ws_size >= 131072) {
        bf16_t* wqb = (bf16_t*)d_ws;          // [384][128] bf16
        bf16_t* wpb = wqb + 49152;            // [128][128] bf16
        wconv_kernel<<<64, 256, 0, stream>>>(qwg, pwg, wqb);
        winattn_kernel<1><<<B, 256, 0, stream>>>(
            xg, mg, qwg, qbg, pwg, pbg, wqb, wpb, nW, outg);
    } else {
        winattn_kernel<0><<<B, 256, 0, stream>>>(
            xg, mg, qwg, qbg, pwg, pbg, nullptr, nullptr, nW, outg);
    }
}